// Round 1
// baseline (368.564 us; speedup 1.0000x reference)
//
#include <hip/hip_runtime.h>
#include <hip/hip_bf16.h>

#define NN 50000
#define EE 800000
#define ETOT 850000   // EE + NN self-loops
#define FIN 500
#define HC 128        // 8 heads * 16 ch
#define NH 8
#define CH 16
#define NC 7

// canonical fp32 weight-buffer offsets
#define OW1  0
#define OAS1 64000
#define OAD1 64128
#define OB1  64256
#define OW2  64384
#define OAS2 65280
#define OAD2 65287
#define OB2  65294
#define WTOT 65301

// MFMA gemm1 tiling
#define GR1  64
#define GK   32
#define KPAD 512
#define ASTR 40
#define BSTR 40

typedef __hip_bfloat16 bf16;
typedef __attribute__((ext_vector_type(8))) short short8;
typedef __attribute__((ext_vector_type(4))) float f32x4;

__device__ __forceinline__ float b2f(const bf16 v) { return __bfloat162float(v); }
__device__ __forceinline__ float lrelu(float v) { return fmaxf(v, 0.2f * v); }
__device__ __forceinline__ float elog(float v) { return __expf(fminf(lrelu(v), 30.f)); }
__device__ __forceinline__ float blo(unsigned w) { return __uint_as_float(w << 16); }
__device__ __forceinline__ float bhi(unsigned w) { return __uint_as_float(w & 0xffff0000u); }
__device__ __forceinline__ unsigned short f2bu(float f)
{
    bf16 h = __float2bfloat16(f);
    return *(unsigned short*)&h;
}

// low-word read: int64 indices are < 2^31, little-endian -> low dword suffices
__device__ __forceinline__ int eread(const void* __restrict__ eidx, long long i, int is64)
{
    if (is64) return ((const int*)eidx)[2 * i];
    return ((const int*)eidx)[i];
}

// ---------------- dtype detection + rowptr sentinel ----------------
__global__ void detect_kernel(const unsigned short* __restrict__ xraw,
                              const unsigned int* __restrict__ eraw,
                              int* __restrict__ flags, int* __restrict__ rowptr)
{
    __shared__ int s_insane, s_oddnz;
    if (threadIdx.x == 0) { s_insane = 0; s_oddnz = 0; }
    __syncthreads();
    int insane = 0;
    for (int i = threadIdx.x; i < 8192; i += 256) {
        const unsigned int bits = ((unsigned int)xraw[i]) << 16;
        const float v = __uint_as_float(bits);
        const float a = fabsf(v);
        const bool sane = (v == 0.0f) || (a >= 1e-30f && a <= 1e4f);
        if (!sane) insane++;
    }
    int oddnz = 0;
    for (int i = threadIdx.x; i < 512; i += 256) {
        if (eraw[2 * i + 1] != 0u) oddnz++;
    }
    atomicAdd(&s_insane, insane);
    atomicAdd(&s_oddnz, oddnz);
    __syncthreads();
    if (threadIdx.x == 0) {
        flags[0] = (s_insane < 256) ? 1 : 0;
        flags[1] = (s_oddnz == 0) ? 1 : 0;
        rowptr[NN] = ETOT;   // sentinel: rowptr holds immutable starts + end
    }
}

// ---------------- canonicalize weights to fp32 + build w1t (merged) ----------------
__global__ void conv_all_kernel(const void* W1, const void* as1, const void* ad1, const void* b1,
                                const void* W2, const void* as2, const void* ad2, const void* b2,
                                float* __restrict__ wc, unsigned short* __restrict__ w1t,
                                const int* __restrict__ flags)
{
    const int i = blockIdx.x * blockDim.x + threadIdx.x;
    const int isbf = flags[0];
    if (i < WTOT) {
        const void* src; int off;
        if (i < OAS1)      { src = W1;  off = i - OW1; }
        else if (i < OAD1) { src = as1; off = i - OAS1; }
        else if (i < OB1)  { src = ad1; off = i - OAD1; }
        else if (i < OW2)  { src = b1;  off = i - OB1; }
        else if (i < OAS2) { src = W2;  off = i - OW2; }
        else if (i < OAD2) { src = as2; off = i - OAS2; }
        else if (i < OB2)  { src = ad2; off = i - OAD2; }
        else               { src = b2;  off = i - OB2; }
        float v;
        if (isbf) v = b2f(((const bf16*)src)[off]);
        else      v = ((const float*)src)[off];
        wc[i] = v;
    }
    if (i < HC * KPAD) {
        const int col = i >> 9;
        const int k   = i & (KPAD - 1);
        float v = 0.f;
        if (k < FIN) {
            if (isbf) v = b2f(((const bf16*)W1)[k * HC + col]);
            else      v = ((const float*)W1)[k * HC + col];
        }
        w1t[i] = f2bu(v);
    }
}

// ---------------- CSR build: histogram of dst ----------------
__global__ void hist_kernel(const void* __restrict__ eidx, int* __restrict__ deg,
                            const int* __restrict__ flags)
{
    const int e = blockIdx.x * blockDim.x + threadIdx.x;
    if (e >= ETOT) return;
    int d;
    if (e < EE) d = eread(eidx, (long long)EE + e, flags[1]);
    else        d = e - EE;
    if ((unsigned)d < (unsigned)NN) atomicAdd(&deg[d], 1);
}

// ---------------- scan k1 ----------------
__global__ void scan_k1_kernel(const int* __restrict__ deg, int* __restrict__ bsum)
{
    __shared__ int lds[256];
    const int i = blockIdx.x * 256 + threadIdx.x;
    lds[threadIdx.x] = (i < NN) ? deg[i] : 0;
    __syncthreads();
    for (int s = 128; s > 0; s >>= 1) {
        if (threadIdx.x < s) lds[threadIdx.x] += lds[threadIdx.x + s];
        __syncthreads();
    }
    if (threadIdx.x == 0) bsum[blockIdx.x] = lds[0];
}

// ---------------- scan k2 ----------------
__global__ void scan_k2_kernel(int* __restrict__ bsum)
{
    __shared__ int a[256], b[256], orig[256];
    const int t = threadIdx.x;
    a[t] = bsum[t]; orig[t] = a[t];
    __syncthreads();
    int* cur = a; int* nxt = b;
    for (int off = 1; off < 256; off <<= 1) {
        nxt[t] = cur[t] + ((t >= off) ? cur[t - off] : 0);
        __syncthreads();
        int* tmp = cur; cur = nxt; nxt = tmp;
    }
    bsum[t] = cur[t] - orig[t];
}

// ---------------- scan k3: rowptr[i] = exclusive start of node i ----------------
__global__ void scan_k3_kernel(const int* __restrict__ deg, const int* __restrict__ bsum,
                               int* __restrict__ rowptr)
{
    __shared__ int a[256], b[256], own[256];
    const int t = threadIdx.x;
    const int i = blockIdx.x * 256 + t;
    const int v = (i < NN) ? deg[i] : 0;
    a[t] = v; own[t] = v;
    __syncthreads();
    int* cur = a; int* nxt = b;
    for (int off = 1; off < 256; off <<= 1) {
        nxt[t] = cur[t] + ((t >= off) ? cur[t - off] : 0);
        __syncthreads();
        int* tmp = cur; cur = nxt; nxt = tmp;
    }
    if (i < NN) rowptr[i] = bsum[blockIdx.x] + cur[t] - own[t];
}

// ---------------- CSR scatter: pos = rowptr[d] + atomic cursor (rank array killed) ----------------
__global__ void scatter_kernel(const void* __restrict__ eidx, const int* __restrict__ rowptr,
                               int* __restrict__ cur, int* __restrict__ esrc_sorted,
                               const int* __restrict__ flags)
{
    const int e = blockIdx.x * blockDim.x + threadIdx.x;
    if (e >= ETOT) return;
    int s, d;
    if (e < EE) {
        s = eread(eidx, e, flags[1]);
        d = eread(eidx, (long long)EE + e, flags[1]);
    } else s = d = e - EE;
    if ((unsigned)s >= (unsigned)NN || (unsigned)d >= (unsigned)NN) return;
    const int pos = rowptr[d] + atomicAdd(&cur[d], 1);
    if ((unsigned)pos < (unsigned)ETOT) esrc_sorted[pos] = s;
}

// ---------------- GEMM1 (MFMA bf16) + fused att1 logits ----------------
__global__ __launch_bounds__(256) void gemm1_mfma_kernel(
    const void* __restrict__ x, const unsigned short* __restrict__ w1t,
    bf16* __restrict__ h1, const float* __restrict__ wc,
    float* __restrict__ a_src1, float* __restrict__ a_dst1,
    const int* __restrict__ flags)
{
    __shared__ unsigned short Asl[GR1 * ASTR];
    __shared__ unsigned short Bsl[HC * BSTR];

    const int t    = threadIdx.x;
    const int wv   = t >> 6;
    const int lane = t & 63;
    const int m15  = lane & 15;
    const int quad = lane >> 4;
    const int r0   = blockIdx.x * GR1;
    const int isbf = flags[0];
    const float* xf = (const float*)x;
    const bf16*  xb = (const bf16*)x;

    const int wr  = (wv >> 1) * 32;
    const int wcb = (wv & 1) * 64;

    f32x4 acc[2][4];
#pragma unroll
    for (int i = 0; i < 2; ++i)
#pragma unroll
        for (int j = 0; j < 4; ++j) acc[i][j] = (f32x4){0.f, 0.f, 0.f, 0.f};

    const int arow = t >> 2;
    const int akk  = (t & 3) * 8;
    const int bcol = t & 127;
    const int bks  = (t >> 7) * 16;

    for (int kt = 0; kt < 16; ++kt) {
        const int k0 = kt * GK;
        {
            const int grow = r0 + arow;
            if (!isbf && grow < NN && (k0 + akk + 8) <= FIN) {
                const size_t base = (size_t)grow * FIN + k0 + akk;
                const float4 v0 = *(const float4*)(xf + base);
                const float4 v1 = *(const float4*)(xf + base + 4);
                uint4 pk;
                pk.x = (unsigned)f2bu(v0.x) | ((unsigned)f2bu(v0.y) << 16);
                pk.y = (unsigned)f2bu(v0.z) | ((unsigned)f2bu(v0.w) << 16);
                pk.z = (unsigned)f2bu(v1.x) | ((unsigned)f2bu(v1.y) << 16);
                pk.w = (unsigned)f2bu(v1.z) | ((unsigned)f2bu(v1.w) << 16);
                *(uint4*)&Asl[arow * ASTR + akk] = pk;
            } else {
#pragma unroll
                for (int j = 0; j < 8; ++j) {
                    const int k = k0 + akk + j;
                    float v = 0.f;
                    if (grow < NN && k < FIN)
                        v = isbf ? b2f(xb[(size_t)grow * FIN + k]) : xf[(size_t)grow * FIN + k];
                    Asl[arow * ASTR + akk + j] = f2bu(v);
                }
            }
        }
        {
            const unsigned short* gp = w1t + (size_t)bcol * KPAD + k0 + bks;
            *(uint4*)&Bsl[bcol * BSTR + bks]     = *(const uint4*)gp;
            *(uint4*)&Bsl[bcol * BSTR + bks + 8] = *(const uint4*)(gp + 8);
        }
        __syncthreads();

        const int ak = quad * 8;
        const short8 a0 = *(const short8*)&Asl[(wr + m15) * ASTR + ak];
        const short8 a1 = *(const short8*)&Asl[(wr + 16 + m15) * ASTR + ak];
#pragma unroll
        for (int ct = 0; ct < 4; ++ct) {
            const short8 b = *(const short8*)&Bsl[(wcb + ct * 16 + m15) * BSTR + ak];
            acc[0][ct] = __builtin_amdgcn_mfma_f32_16x16x32_bf16(a0, b, acc[0][ct], 0, 0, 0);
            acc[1][ct] = __builtin_amdgcn_mfma_f32_16x16x32_bf16(a1, b, acc[1][ct], 0, 0, 0);
        }
        __syncthreads();
    }

    // epilogue: store h1 + fused att1 (quad-local shuffle reduce over the 16 channels)
    const int hc0 = wcb >> 4;   // first head covered by this wave's 64 cols
    float asw[4], adw[4];
#pragma unroll
    for (int ct = 0; ct < 4; ++ct) {
        asw[ct] = wc[OAS1 + (hc0 + ct) * CH + m15];
        adw[ct] = wc[OAD1 + (hc0 + ct) * CH + m15];
    }
#pragma unroll
    for (int rt = 0; rt < 2; ++rt) {
#pragma unroll
        for (int reg = 0; reg < 4; ++reg) {
            const int row = r0 + wr + rt * 16 + quad * 4 + reg;
            const bool ok = (row < NN);
            bf16* hp = h1 + (size_t)row * HC;
#pragma unroll
            for (int ct = 0; ct < 4; ++ct) {
                const float v = acc[rt][ct][reg];
                if (ok) hp[wcb + ct * 16 + m15] = __float2bfloat16(v);
                float s = v * asw[ct];
                float d = v * adw[ct];
                // reduce across the 16 lanes of this quad (xor of lane bits 0..3)
                s += __shfl_xor(s, 1);  d += __shfl_xor(d, 1);
                s += __shfl_xor(s, 2);  d += __shfl_xor(d, 2);
                s += __shfl_xor(s, 4);  d += __shfl_xor(d, 4);
                s += __shfl_xor(s, 8);  d += __shfl_xor(d, 8);
                if (ok && m15 == 0) {
                    a_src1[row * NH + hc0 + ct] = s;
                    a_dst1[row * NH + hc0 + ct] = d;
                }
            }
        }
    }
}

// ---------------- layer-1 fused gather + fused GEMM2/bias/relu + fused att2 ----------------
__global__ __launch_bounds__(256) void gather1_kernel(
    const int* __restrict__ rowptr, const int* __restrict__ esrc_sorted,
    const float* __restrict__ a_src, const float* __restrict__ a_dst,
    const bf16* __restrict__ h1, const float* __restrict__ wc,
    float* __restrict__ h2, float* __restrict__ a_src2, float* __restrict__ a_dst2)
{
    __shared__ float W2s[HC * NC];
    __shared__ float B1s[HC];
    for (int i = threadIdx.x; i < HC * NC; i += 256) W2s[i] = wc[OW2 + i];
    if (threadIdx.x < HC) B1s[threadIdx.x] = wc[OB1 + threadIdx.x];
    __syncthreads();

    const int node = blockIdx.x * 4 + (threadIdx.x >> 6);
    if (node >= NN) return;
    const int lane = threadIdx.x & 63;
    const int h = lane >> 3;
    const float ad = a_dst[node * NH + h];
    const int start = rowptr[node];
    const int end   = rowptr[node + 1];
    float acc0 = 0.f, acc1 = 0.f, den = 0.f;
    int i = start;
    for (; i + 8 <= end; i += 8) {
        int   sv[8];
        float ev[8];
        unsigned wv[8];
#pragma unroll
        for (int j = 0; j < 8; ++j) sv[j] = esrc_sorted[i + j];
#pragma unroll
        for (int j = 0; j < 8; ++j) ev[j] = a_src[sv[j] * NH + h];
#pragma unroll
        for (int j = 0; j < 8; ++j) wv[j] = *(const unsigned*)(h1 + (size_t)sv[j] * HC + 2 * lane);
#pragma unroll
        for (int j = 0; j < 8; ++j) {
            const float n = elog(ev[j] + ad);
            acc0 += n * blo(wv[j]);
            acc1 += n * bhi(wv[j]);
            den  += n;
        }
    }
    for (; i < end; ++i) {
        const int s = esrc_sorted[i];
        const float num = elog(a_src[s * NH + h] + ad);
        const unsigned w = *(const unsigned*)(h1 + (size_t)s * HC + 2 * lane);
        acc0 += num * blo(w);
        acc1 += num * bhi(w);
        den  += num;
    }
    const float inv = 1.f / (den + 1e-16f);

    // fused GEMM2: this wave holds the whole out1 row (2 channels / lane).
    const int k0 = 2 * lane;
    const float r0v = fmaxf(acc0 * inv + B1s[k0],     0.f);
    const float r1v = fmaxf(acc1 * inv + B1s[k0 + 1], 0.f);
    float p[NC];
#pragma unroll
    for (int c = 0; c < NC; ++c)
        p[c] = r0v * W2s[k0 * NC + c] + r1v * W2s[(k0 + 1) * NC + c];
    // 64-lane butterfly reduce (7 channels)
#pragma unroll
    for (int m = 1; m < 64; m <<= 1) {
#pragma unroll
        for (int c = 0; c < NC; ++c) p[c] += __shfl_xor(p[c], m);
    }
    if (lane == 0) {
        float ps = 0.f, pd = 0.f;
        float* hp = h2 + (size_t)node * NC;
#pragma unroll
        for (int c = 0; c < NC; ++c) {
            hp[c] = p[c];
            ps += p[c] * wc[OAS2 + c];
            pd += p[c] * wc[OAD2 + c];
        }
        a_src2[node] = ps;
        a_dst2[node] = pd;
    }
}

// ---------------- layer-2 fused gather ----------------
__global__ void gather2_kernel(
    const int* __restrict__ rowptr, const int* __restrict__ esrc_sorted,
    const float* __restrict__ a_src, const float* __restrict__ a_dst,
    const float* __restrict__ h2, const float* __restrict__ wc,
    void* __restrict__ out, const int* __restrict__ flags)
{
    const int node = blockIdx.x * 32 + (threadIdx.x >> 3);
    if (node >= NN) return;
    const int c = threadIdx.x & 7;
    const float ad = a_dst[node];
    const int start = rowptr[node];
    const int end   = rowptr[node + 1];
    const int cc = (c < NC) ? c : 0;
    float acc = 0.f, den = 0.f;
    int i = start;
    for (; i + 4 <= end; i += 4) {
        const int s0 = esrc_sorted[i + 0];
        const int s1 = esrc_sorted[i + 1];
        const int s2 = esrc_sorted[i + 2];
        const int s3 = esrc_sorted[i + 3];
        const float e0 = a_src[s0];
        const float e1 = a_src[s1];
        const float e2 = a_src[s2];
        const float e3 = a_src[s3];
        const float v0 = h2[s0 * NC + cc];
        const float v1 = h2[s1 * NC + cc];
        const float v2 = h2[s2 * NC + cc];
        const float v3 = h2[s3 * NC + cc];
        const float n0 = elog(e0 + ad);
        const float n1 = elog(e1 + ad);
        const float n2 = elog(e2 + ad);
        const float n3 = elog(e3 + ad);
        acc += n0 * v0 + n1 * v1 + n2 * v2 + n3 * v3;
        den += n0 + n1 + n2 + n3;
    }
    for (; i < end; ++i) {
        const int s = esrc_sorted[i];
        const float num = elog(a_src[s] + ad);
        den += num;
        acc += num * h2[s * NC + cc];
    }
    if (c >= NC) return;
    const float v = acc / (den + 1e-16f) + wc[OB2 + c];
    if (flags[0]) ((bf16*)out)[node * NC + c] = __float2bfloat16(v);
    else          ((float*)out)[node * NC + c] = v;
}

extern "C" void kernel_launch(void* const* d_in, const int* in_sizes, int n_in,
                              void* d_out, int out_size, void* d_ws, size_t ws_size,
                              hipStream_t stream)
{
    const void* x        = d_in[0];
    const void* eidx     = d_in[1];
    const void* W1       = d_in[2];
    const void* att_src1 = d_in[3];
    const void* att_dst1 = d_in[4];
    const void* b1       = d_in[5];
    const void* W2       = d_in[6];
    const void* att_src2 = d_in[7];
    const void* att_dst2 = d_in[8];
    const void* b2       = d_in[9];

    float* ws = (float*)d_ws;
    size_t o = 0;
    int*   flags  = (int*)(ws + o);            o += 16;
    float* wc     = ws + o;                    o += 65312;
    unsigned short* w1t = (unsigned short*)(ws + o); o += (HC * KPAD) / 2;
    int*   deg    = (int*)(ws + o);            o += 50000;
    int*   cur    = (int*)(ws + o);            o += 50000;   // contiguous with deg for one memset
    int*   rowptr = (int*)(ws + o);            o += 50016;
    int*   bsum   = (int*)(ws + o);            o += 256;
    int*   esrt   = (int*)(ws + o);            o += 850000;
    bf16*  h1     = (bf16*)(ws + o);           o += (size_t)NN * HC / 2;
    float* a_src1 = ws + o;                    o += (size_t)NN * NH;
    float* a_dst1 = ws + o;                    o += (size_t)NN * NH;
    float* h2     = ws + o;                    o += (size_t)NN * NC;
    float* a_src2 = ws + o;                    o += NN;
    float* a_dst2 = ws + o;                    o += NN;
    // ~22 MB of d_ws used

    detect_kernel<<<1, 256, 0, stream>>>((const unsigned short*)x, (const unsigned int*)eidx,
                                         flags, rowptr);
    conv_all_kernel<<<(HC * KPAD + 255) / 256, 256, 0, stream>>>(
        W1, att_src1, att_dst1, b1, W2, att_src2, att_dst2, b2, wc, w1t, flags);
    hipMemsetAsync(deg, 0, 2 * (size_t)NN * sizeof(int), stream);
    hist_kernel<<<(ETOT + 255) / 256, 256, 0, stream>>>(eidx, deg, flags);
    scan_k1_kernel<<<(NN + 255) / 256, 256, 0, stream>>>(deg, bsum);
    scan_k2_kernel<<<1, 256, 0, stream>>>(bsum);
    scan_k3_kernel<<<(NN + 255) / 256, 256, 0, stream>>>(deg, bsum, rowptr);
    scatter_kernel<<<(ETOT + 255) / 256, 256, 0, stream>>>(eidx, rowptr, cur, esrt, flags);

    gemm1_mfma_kernel<<<(NN + GR1 - 1) / GR1, 256, 0, stream>>>(x, w1t, h1, wc,
                                                                a_src1, a_dst1, flags);
    gather1_kernel<<<(NN + 3) / 4, 256, 0, stream>>>(rowptr, esrt, a_src1, a_dst1, h1, wc,
                                                     h2, a_src2, a_dst2);
    gather2_kernel<<<(NN + 31) / 32, 256, 0, stream>>>(rowptr, esrt, a_src2, a_dst2, h2, wc,
                                                       d_out, flags);
}